// Round 4
// baseline (460.414 us; speedup 1.0000x reference)
//
#include <hip/hip_runtime.h>
#include <math.h>

#define B 64
#define T 4096
#define D 256
#define U 256

typedef __attribute__((ext_vector_type(8))) short s16x8;
typedef __attribute__((ext_vector_type(4))) float f32x4;

#define MT 32                   // rows per step
#define SPB 32                  // steps per block
#define NBLK ((B*T)/(MT*SPB))   // 256 blocks = 1/CU
#define RQ 33                   // LDS row stride in uint4 (32 data + 1 pad)

// DPP cross-lane add (VALU pipe): v += lane-permuted v (within 16-lane row)
#define DPP_ADD(v, ctrl)                                                     \
  v += __int_as_float(__builtin_amdgcn_update_dpp(                           \
      0, __float_as_int(v), ctrl, 0xF, 0xF, true))

// convert 8 consecutive f32 (2 float4) to hi/lo bf16 uint4s, write LDS cell
__device__ __forceinline__ void stage16(uint4* bufH, uint4* bufL,
                                        const float4* rg, int rowg, int c8) {
  uint4 hi, lo;
  unsigned* hp = (unsigned*)&hi;
  unsigned* lp = (unsigned*)&lo;
  const float* f = (const float*)rg;
#pragma unroll
  for (int jw = 0; jw < 4; ++jw) {
    const unsigned u0 = __float_as_uint(f[2 * jw]);
    const unsigned u1 = __float_as_uint(f[2 * jw + 1]);
    hp[jw] = (u0 >> 16) | (u1 & 0xffff0000u);
    const float l0 = f[2 * jw]     - __uint_as_float(u0 & 0xffff0000u);
    const float l1 = f[2 * jw + 1] - __uint_as_float(u1 & 0xffff0000u);
    lp[jw] = (__float_as_uint(l0) >> 16) | (__float_as_uint(l1) & 0xffff0000u);
  }
  bufH[rowg * RQ + c8] = hi;
  bufL[rowg * RQ + c8] = lo;
}

// ============ fused scores + online context, 16x16x32 MFMA ==================
// s[b,t] = sum_u tanh((A@(W1+W2))[u]) * v[u];  w = e^s (|s| <= ~13, no max
// subtraction needed).  16 waves x 16 u-cols: B-frags cost 64 VGPR (vs 128
// at 32x32) -> 4 waves/SIMD occupancy.  One barrier per step: double-buffered
// LDS tiles; wctx at lag-1 re-reads its A-rows from global (L2-hot) so no
// third buffer and no register copies are needed.
__global__ __launch_bounds__(1024, 4) void scores_ctx_kernel(
    const float* __restrict__ A,    // [B*T, D]
    const float* __restrict__ W1,   // [D, U]
    const float* __restrict__ W2,   // [D, U]
    const float* __restrict__ v,    // [U]
    float* __restrict__ w_out,      // [B*T] unnormalized weights e^s
    float* __restrict__ part,       // [NBLK][D] ctx partials (unnormalized)
    float* __restrict__ zpart)      // [NBLK] sum of w over block's rows
{
  __shared__ uint4 tiles[4][32 * RQ];  // [2 bufs][H,L] 32 rows x 256 bf16
  __shared__ float red[2][32][16];     // [parity][row][wave] score partials
  __shared__ float zw[32];

  const int tid  = threadIdx.x;
  const int lane = tid & 63;
  const int wv   = tid >> 6;       // 0..15
  const int l15  = lane & 15;
  const int g4   = lane >> 4;      // 0..3
  const int rowg = tid >> 5;       // 0..31  (staging / wctx row)
  const int c8   = tid & 31;       // 8-float column block

  // ---- register B-fragments from W1+W2 (16x16x32: k = 32s + 8*g4 + j) ----
  const int n = wv * 16 + l15;
  s16x8 Bh[8], Bl[8];
#pragma unroll
  for (int s = 0; s < 8; ++s) {
    s16x8 bh, bl;
#pragma unroll
    for (int j = 0; j < 8; ++j) {
      const int k = s * 32 + g4 * 8 + j;
      const float w = W1[k * 256 + n] + W2[k * 256 + n];
      const unsigned uw = __float_as_uint(w);
      const float wl = w - __uint_as_float(uw & 0xffff0000u);
      bh[j] = (short)(uw >> 16);
      bl[j] = (short)(__float_as_uint(wl) >> 16);
    }
    Bh[s] = bh; Bl[s] = bl;
  }
  const float vv = v[n];

  float acc[8] = {0.f, 0.f, 0.f, 0.f, 0.f, 0.f, 0.f, 0.f};
  float zacc = 0.f;

  const size_t row0 = (size_t)blockIdx.x * (MT * SPB);
  float4 rg[2];
  {
    const float4* src = (const float4*)(A + (row0 + rowg) * 256 + c8 * 8);
    rg[0] = src[0]; rg[1] = src[1];
  }
  stage16(tiles[0], tiles[1], rg, rowg, c8);
  {
    const float4* src = (const float4*)(A + (row0 + MT + rowg) * 256 + c8 * 8);
    rg[0] = src[0]; rg[1] = src[1];
  }
  __syncthreads();

  int cur = 0;
  for (int step = 0; step < SPB; ++step) {
    const int par = step & 1;

    // ---- wctx(step-1): w from red, A-rows re-read from global (L2-hot) ----
    if (step > 0) {
      const size_t rowb = row0 + (size_t)(step - 1) * MT;
      const float4* rp = (const float4*)&red[par ^ 1][rowg][0];
      const float4 q0 = rp[0], q1 = rp[1], q2 = rp[2], q3 = rp[3];
      const float s8 = ((q0.x + q0.y) + (q0.z + q0.w)) +
                       ((q1.x + q1.y) + (q1.z + q1.w)) +
                       ((q2.x + q2.y) + (q2.z + q2.w)) +
                       ((q3.x + q3.y) + (q3.z + q3.w));
      const float w = __expf(s8);
      if (c8 == 0) { w_out[rowb + rowg] = w; zacc += w; }
      const float4* src = (const float4*)(A + (rowb + rowg) * 256 + c8 * 8);
      const float4 xa = src[0], xb = src[1];
      acc[0] = fmaf(w, xa.x, acc[0]); acc[1] = fmaf(w, xa.y, acc[1]);
      acc[2] = fmaf(w, xa.z, acc[2]); acc[3] = fmaf(w, xa.w, acc[3]);
      acc[4] = fmaf(w, xb.x, acc[4]); acc[5] = fmaf(w, xb.y, acc[5]);
      acc[6] = fmaf(w, xb.z, acc[6]); acc[7] = fmaf(w, xb.w, acc[7]);
    }

    // ---- MFMA: two 16-row tiles, 3-product split-bf16 single chains ----
    f32x4 dd[2] = {};
    {
      const uint4* cH = tiles[cur * 2];
      const uint4* cL = tiles[cur * 2 + 1];
#pragma unroll
      for (int s = 0; s < 8; ++s) {
        const int ci = s * 4 + g4;
        const uint4 qh0 = cH[l15 * RQ + ci];
        const uint4 ql0 = cL[l15 * RQ + ci];
        const uint4 qh1 = cH[(l15 + 16) * RQ + ci];
        const uint4 ql1 = cL[(l15 + 16) * RQ + ci];
        const s16x8 ah0 = __builtin_bit_cast(s16x8, qh0);
        const s16x8 al0 = __builtin_bit_cast(s16x8, ql0);
        const s16x8 ah1 = __builtin_bit_cast(s16x8, qh1);
        const s16x8 al1 = __builtin_bit_cast(s16x8, ql1);
        dd[0] = __builtin_amdgcn_mfma_f32_16x16x32_bf16(ah0, Bh[s], dd[0], 0, 0, 0);
        dd[1] = __builtin_amdgcn_mfma_f32_16x16x32_bf16(ah1, Bh[s], dd[1], 0, 0, 0);
        dd[0] = __builtin_amdgcn_mfma_f32_16x16x32_bf16(ah0, Bl[s], dd[0], 0, 0, 0);
        dd[1] = __builtin_amdgcn_mfma_f32_16x16x32_bf16(ah1, Bl[s], dd[1], 0, 0, 0);
        dd[0] = __builtin_amdgcn_mfma_f32_16x16x32_bf16(al0, Bh[s], dd[0], 0, 0, 0);
        dd[1] = __builtin_amdgcn_mfma_f32_16x16x32_bf16(al1, Bh[s], dd[1], 0, 0, 0);
      }
    }

    // ---- stage next tile into other buffer + prefetch following tile ----
    if (step + 1 < SPB)
      stage16(tiles[(cur ^ 1) * 2], tiles[(cur ^ 1) * 2 + 1], rg, rowg, c8);
    if (step + 2 < SPB) {
      const float4* src =
          (const float4*)(A + (row0 + (size_t)(step + 2) * MT + rowg) * 256 + c8 * 8);
      rg[0] = src[0]; rg[1] = src[1];
    }

    // ---- epilogue: tanh, *v[u], reduce 16 u-lanes (4 DPP, within-16) ----
#pragma unroll
    for (int t = 0; t < 2; ++t) {
#pragma unroll
      for (int r = 0; r < 4; ++r) {
        const float x = dd[t][r];
        const float e = __expf(x + x);                             // e^{2x}
        float p = (1.f - 2.f * __builtin_amdgcn_rcpf(e + 1.f)) * vv;  // tanh*v
        DPP_ADD(p, 0xB1);   // + lane^1
        DPP_ADD(p, 0x4E);   // + lane^2
        DPP_ADD(p, 0x141);  // row_half_mirror: 8-sum
        DPP_ADD(p, 0x140);  // row_mirror: 16-sum
        if (l15 == 0) red[par][16 * t + 4 * g4 + r][wv] = p;
      }
    }
    __syncthreads();
    cur ^= 1;
  }

  // ---- drain: wctx for the last step ----
  {
    const size_t rowb = row0 + (size_t)(SPB - 1) * MT;
    const float4* rp = (const float4*)&red[(SPB - 1) & 1][rowg][0];
    const float4 q0 = rp[0], q1 = rp[1], q2 = rp[2], q3 = rp[3];
    const float s8 = ((q0.x + q0.y) + (q0.z + q0.w)) +
                     ((q1.x + q1.y) + (q1.z + q1.w)) +
                     ((q2.x + q2.y) + (q2.z + q2.w)) +
                     ((q3.x + q3.y) + (q3.z + q3.w));
    const float w = __expf(s8);
    if (c8 == 0) { w_out[rowb + rowg] = w; zacc += w; }
    const float4* src = (const float4*)(A + (rowb + rowg) * 256 + c8 * 8);
    const float4 xa = src[0], xb = src[1];
    acc[0] = fmaf(w, xa.x, acc[0]); acc[1] = fmaf(w, xa.y, acc[1]);
    acc[2] = fmaf(w, xa.z, acc[2]); acc[3] = fmaf(w, xa.w, acc[3]);
    acc[4] = fmaf(w, xb.x, acc[4]); acc[5] = fmaf(w, xb.y, acc[5]);
    acc[6] = fmaf(w, xb.z, acc[6]); acc[7] = fmaf(w, xb.w, acc[7]);
  }

  // ---- block-end reductions (alias tile LDS; tiles dead after last bar) ----
  float* wb = (float*)&tiles[0][0];   // [32 rowg][256 cols] = 32 KB
#pragma unroll
  for (int j = 0; j < 8; ++j) wb[rowg * 256 + c8 * 8 + j] = acc[j];
  if (c8 == 0) zw[rowg] = zacc;
  __syncthreads();

  if (tid < 256) {
    float ssum = 0.f;
#pragma unroll
    for (int g = 0; g < 32; ++g) ssum += wb[g * 256 + tid];
    part[blockIdx.x * 256 + tid] = ssum;
  }
  if (tid == 0) {
    float z = 0.f;
#pragma unroll
    for (int i = 0; i < 32; ++i) z += zw[i];
    zpart[blockIdx.x] = z;
  }
}

// ============ finalize: Z per batch, scale ctx + attn =======================
#define BPB (NBLK / B)   // blocks per batch = 4
__global__ __launch_bounds__(1024) void finalize_kernel(
    const float* __restrict__ part,   // [NBLK][D] = [B*BPB][D]
    const float* __restrict__ zpart,  // [NBLK]
    float* __restrict__ attn,         // [B*T] in: w, out: w/Z
    float* __restrict__ ctx)          // [B*D]
{
  const int b = blockIdx.x;
  const int tid = threadIdx.x;
  __shared__ float shinv;
  if (tid == 0) {
    float z = 0.f;
#pragma unroll
    for (int c = 0; c < BPB; ++c) z += zpart[b * BPB + c];
    shinv = 1.0f / z;
  }
  __syncthreads();
  const float iz = shinv;

  if (tid < D) {
    float s = 0.f;
#pragma unroll
    for (int c = 0; c < BPB; ++c) s += part[(b * BPB + c) * D + tid];
    ctx[b * D + tid] = s * iz;
  }

  float4* row = (float4*)(attn + (long)b * T);
  float4 w4 = row[tid];                 // 1024 threads * 4 = T
  w4.x *= iz; w4.y *= iz; w4.z *= iz; w4.w *= iz;
  row[tid] = w4;
}

extern "C" void kernel_launch(void* const* d_in, const int* in_sizes, int n_in,
                              void* d_out, int out_size, void* d_ws, size_t ws_size,
                              hipStream_t stream) {
    const float* lstm = (const float*)d_in[0];  // [B,T,D]
    const float* W1   = (const float*)d_in[1];  // [D,U]
    const float* W2   = (const float*)d_in[2];  // [D,U]
    const float* v    = (const float*)d_in[3];  // [U,1]

    float* out  = (float*)d_out;
    float* ctx  = out;            // [B*D]
    float* attn = out + B * D;    // [B*T]

    float* part  = (float*)d_ws;          // NBLK*D floats
    float* zpart = part + NBLK * D;       // NBLK floats

    scores_ctx_kernel<<<NBLK, 1024, 0, stream>>>(lstm, W1, W2, v, attn, part, zpart);
    finalize_kernel<<<B, 1024, 0, stream>>>(part, zpart, attn, ctx);
}